// Round 1
// baseline (20.316 us; speedup 1.0000x reference)
//
#include <hip/hip_runtime.h>
#include <hip/hip_bf16.h>

#define B_ 64
#define N_ 576
#define D_ 384
#define K_ 4096

// Kernel 1: per-row projection. y[r][0..3] = { z_r . W[0][0:384],
//                                              z_r . W[1][0:384],
//                                              z_r . W[0][384:768],
//                                              z_r . W[1][384:768] }
// One wave (64 lanes) per row; lane i covers columns i, i+64, ..., i+320.
__global__ __launch_bounds__(256) void partvit_proj(const float* __restrict__ z,
                                                    const float* __restrict__ W,
                                                    float* __restrict__ y) {
    const int wave = (blockIdx.x * blockDim.x + threadIdx.x) >> 6;  // row id
    const int lane = threadIdx.x & 63;
    if (wave >= B_ * N_) return;

    const float* zr = z + (size_t)wave * D_;
    float a0 = 0.f, a1 = 0.f, a2 = 0.f, a3 = 0.f;
#pragma unroll
    for (int j = 0; j < D_ / 64; ++j) {
        const int c = lane + 64 * j;
        const float x = zr[c];
        a0 += x * W[c];            // W[0][c]
        a1 += x * W[768 + c];      // W[1][c]
        a2 += x * W[384 + c];      // W[0][384+c]
        a3 += x * W[1152 + c];     // W[1][384+c]
    }
    // 64-lane butterfly reduce (wave = 64 on gfx950)
#pragma unroll
    for (int off = 32; off > 0; off >>= 1) {
        a0 += __shfl_xor(a0, off);
        a1 += __shfl_xor(a1, off);
        a2 += __shfl_xor(a2, off);
        a3 += __shfl_xor(a3, off);
    }
    if (lane == 0) {
        float4 v;
        v.x = a0; v.y = a1; v.z = a2; v.w = a3;
        *reinterpret_cast<float4*>(y + (size_t)wave * 4) = v;
    }
}

// Kernel 2: gather + bias + index pass-through.
// out[b,k,t]      = y[b,i0][t] + y[b,i1][2+t] + bias[t]
// idx_out[b,k,m]  = (float)indices[b,k,m]
__global__ __launch_bounds__(256) void partvit_gather(const int* __restrict__ idx,
                                                      const float* __restrict__ y,
                                                      const float* __restrict__ bias,
                                                      float* __restrict__ out,
                                                      float* __restrict__ idx_out) {
    const int t = blockIdx.x * blockDim.x + threadIdx.x;  // pair id in [0, B*K)
    if (t >= B_ * K_) return;
    const int b = t >> 12;  // K = 4096

    const int2 p = reinterpret_cast<const int2*>(idx)[t];
    const float* yb = y + (size_t)b * N_ * 4;

    const float2 y0 = *reinterpret_cast<const float2*>(yb + (size_t)p.x * 4);      // [a0,a1] of i0
    const float2 y1 = *reinterpret_cast<const float2*>(yb + (size_t)p.y * 4 + 2);  // [a2,a3] of i1

    const float b0 = bias[0], b1 = bias[1];

    float2 o;
    o.x = y0.x + y1.x + b0;
    o.y = y0.y + y1.y + b1;
    reinterpret_cast<float2*>(out)[t] = o;

    float2 io;
    io.x = (float)p.x;
    io.y = (float)p.y;
    reinterpret_cast<float2*>(idx_out)[t] = io;
}

extern "C" void kernel_launch(void* const* d_in, const int* in_sizes, int n_in,
                              void* d_out, int out_size, void* d_ws, size_t ws_size,
                              hipStream_t stream) {
    const float* z    = (const float*)d_in[0];
    const int*   idx  = (const int*)d_in[1];
    const float* W    = (const float*)d_in[2];
    const float* bias = (const float*)d_in[3];

    float* out     = (float*)d_out;                    // [B,K,2] floats
    float* idx_out = (float*)d_out + (size_t)B_ * K_ * 2;  // indices as float, [B,K,2]
    float* y       = (float*)d_ws;                     // [B*N, 4] floats = 590 KB

    // Kernel 1: 36864 rows, 1 wave/row, 4 waves/block -> 9216 blocks
    const int rows = B_ * N_;
    partvit_proj<<<(rows + 3) / 4, 256, 0, stream>>>(z, W, y);

    // Kernel 2: 262144 pairs, 1 thread/pair -> 1024 blocks
    const int pairs = B_ * K_;
    partvit_gather<<<(pairs + 255) / 256, 256, 0, stream>>>(idx, y, bias, out, idx_out);
}

// Round 2
// 19.473 us; speedup vs baseline: 1.0433x; 1.0433x over previous
//
#include <hip/hip_runtime.h>
#include <hip/hip_bf16.h>

#define B_ 64
#define N_ 576
#define D_ 384
#define K_ 4096

// Kernel 1: per-row projection, y[r] = { z_r.W0[:384], z_r.W1[:384], z_r.W0[384:], z_r.W1[384:] }
// Half-wave (32 lanes) per row; lane s owns float4-columns s*3..s*3+2 with the
// corresponding 12 W float4s held in registers (no W loads in the loop).
// Grid-stride over row-pairs (2 rows per wave iteration).
__global__ __launch_bounds__(256) void partvit_proj(const float* __restrict__ z,
                                                    const float* __restrict__ W,
                                                    float* __restrict__ y) {
    const int wid  = (blockIdx.x * blockDim.x + threadIdx.x) >> 6;  // wave id
    const int lane = threadIdx.x & 63;
    const int h = lane >> 5;   // which row of the pair
    const int s = lane & 31;   // column-chunk owner within the row

    const float4* Wq = reinterpret_cast<const float4*>(W);
    const float4* zq = reinterpret_cast<const float4*>(z);

    // W[t][f]: t*768+f. float4 view: W0[:384]=Wq[0..95], W0[384:]=Wq[96..191],
    //                                W1[:384]=Wq[192..287], W1[384:]=Wq[288..383]
    float4 w0a[3], w1a[3], w0b[3], w1b[3];
#pragma unroll
    for (int m = 0; m < 3; ++m) {
        const int c4 = s * 3 + m;
        w0a[m] = Wq[c4];
        w0b[m] = Wq[96 + c4];
        w1a[m] = Wq[192 + c4];
        w1b[m] = Wq[288 + c4];
    }

    const int npairs = (B_ * N_) / 2;                       // 18432 row-pairs
    const int nwaves = (gridDim.x * blockDim.x) >> 6;
    for (int pid = wid; pid < npairs; pid += nwaves) {
        const int row = pid * 2 + h;
        const float4* zr = zq + (size_t)row * 96 + s * 3;
        float a0 = 0.f, a1 = 0.f, a2 = 0.f, a3 = 0.f;
#pragma unroll
        for (int m = 0; m < 3; ++m) {
            const float4 v = zr[m];
            a0 += v.x * w0a[m].x + v.y * w0a[m].y + v.z * w0a[m].z + v.w * w0a[m].w;
            a1 += v.x * w1a[m].x + v.y * w1a[m].y + v.z * w1a[m].z + v.w * w1a[m].w;
            a2 += v.x * w0b[m].x + v.y * w0b[m].y + v.z * w0b[m].z + v.w * w0b[m].w;
            a3 += v.x * w1b[m].x + v.y * w1b[m].y + v.z * w1b[m].z + v.w * w1b[m].w;
        }
        // reduce across the 32 lanes of this half-wave (xor offsets stay within half)
#pragma unroll
        for (int off = 16; off > 0; off >>= 1) {
            a0 += __shfl_xor(a0, off);
            a1 += __shfl_xor(a1, off);
            a2 += __shfl_xor(a2, off);
            a3 += __shfl_xor(a3, off);
        }
        if (s == 0) {
            float4 v;
            v.x = a0; v.y = a1; v.z = a2; v.w = a3;
            reinterpret_cast<float4*>(y)[row] = v;
        }
    }
}

// Kernel 2: gather + bias + index pass-through.
// out[b,k,t]      = y[b,i0][t] + y[b,i1][2+t] + bias[t]
// idx_out[b,k,m]  = (float)indices[b,k,m]
__global__ __launch_bounds__(256) void partvit_gather(const int* __restrict__ idx,
                                                      const float* __restrict__ y,
                                                      const float* __restrict__ bias,
                                                      float* __restrict__ out,
                                                      float* __restrict__ idx_out) {
    const int t = blockIdx.x * blockDim.x + threadIdx.x;  // pair id in [0, B*K)
    if (t >= B_ * K_) return;
    const int b = t >> 12;  // K = 4096

    const int2 p = reinterpret_cast<const int2*>(idx)[t];
    const float* yb = y + (size_t)b * N_ * 4;

    const float2 y0 = *reinterpret_cast<const float2*>(yb + (size_t)p.x * 4);      // [a0,a1] of i0
    const float2 y1 = *reinterpret_cast<const float2*>(yb + (size_t)p.y * 4 + 2);  // [a2,a3] of i1

    const float b0 = bias[0], b1 = bias[1];

    float2 o;
    o.x = y0.x + y1.x + b0;
    o.y = y0.y + y1.y + b1;
    reinterpret_cast<float2*>(out)[t] = o;

    float2 io;
    io.x = (float)p.x;
    io.y = (float)p.y;
    reinterpret_cast<float2*>(idx_out)[t] = io;
}

extern "C" void kernel_launch(void* const* d_in, const int* in_sizes, int n_in,
                              void* d_out, int out_size, void* d_ws, size_t ws_size,
                              hipStream_t stream) {
    const float* z    = (const float*)d_in[0];
    const int*   idx  = (const int*)d_in[1];
    const float* W    = (const float*)d_in[2];
    const float* bias = (const float*)d_in[3];

    float* out     = (float*)d_out;                        // [B,K,2] floats
    float* idx_out = (float*)d_out + (size_t)B_ * K_ * 2;  // indices as float, [B,K,2]
    float* y       = (float*)d_ws;                         // [B*N, 4] floats = 590 KB

    // Kernel 1: 4096 waves grid-striding over 18432 row-pairs
    partvit_proj<<<1024, 256, 0, stream>>>(z, W, y);

    // Kernel 2: 262144 pairs, 1 thread/pair -> 1024 blocks
    const int pairs = B_ * K_;
    partvit_gather<<<(pairs + 255) / 256, 256, 0, stream>>>(idx, y, bias, out, idx_out);
}